// Round 2
// baseline (4058.738 us; speedup 1.0000x reference)
//
#include <hip/hip_runtime.h>
#include <hip/hip_bf16.h>
#include <cmath>

using u16 = unsigned short;
using bf16x8 = __attribute__((ext_vector_type(8))) __bf16;
using f32x4 = __attribute__((ext_vector_type(4))) float;

__device__ __forceinline__ u16 f2bf(float f) {
  union { float f; unsigned int i; } x; x.f = f;
  unsigned int r = x.i + 0x7FFFu + ((x.i >> 16) & 1u);
  return (u16)(r >> 16);
}
__device__ __forceinline__ float bf2f(u16 u) {
  union { unsigned int i; float f; } x; x.i = (unsigned int)u << 16; return x.f;
}

// convert 8 consecutive fp32 -> 8 bf16 (RNE) and store 16B to LDS
__device__ __forceinline__ void cvt8_to_lds(const float* __restrict__ p, u16* dst) {
  float4 a = *(const float4*)p;
  float4 b = *(const float4*)(p + 4);
  u16 t[8] = {f2bf(a.x), f2bf(a.y), f2bf(a.z), f2bf(a.w),
              f2bf(b.x), f2bf(b.y), f2bf(b.z), f2bf(b.w)};
  *(uint4*)dst = *(uint4*)t;
}

// boxes[row][f] = tanh(sum_q inp[row][q] * Wb[f][q] + bb[f]), row = b*64+i  (fp32 in, bf16 out)
__global__ void box_all_kernel(const float* __restrict__ inp, const float* __restrict__ Wb,
                               const float* __restrict__ bb, u16* __restrict__ boxes) {
  int row = blockIdx.x;
  int f = threadIdx.x;
  __shared__ float s_in[12];
  if (f < 12) s_in[f] = inp[(long)row * 12 + f];
  __syncthreads();
  float a = bb[f];
#pragma unroll
  for (int q = 0; q < 12; ++q) a += s_in[q] * Wb[f * 12 + q];
  boxes[(long)row * 512 + f] = f2bf(tanhf(a));
}

__global__ void box_one_kernel(const float* __restrict__ inp, const float* __restrict__ Wb,
                               const float* __restrict__ bb, int bp, u16* __restrict__ outBox) {
  int b = blockIdx.x;
  int f = threadIdx.x;
  __shared__ float s_in[12];
  if (f < 12) s_in[f] = inp[((long)b * 64 + bp) * 12 + f];
  __syncthreads();
  float a = bb[f];
#pragma unroll
  for (int q = 0; q < 12; ++q) a += s_in[q] * Wb[f * 12 + q];
  outBox[(long)b * 512 + f] = f2bf(tanhf(a));
}

// C[m][n] = tanh( A1@W1^T (+ A2@W2^T) + bias[n] (+ sym path) )
// A: bf16, M x K row-major, row stride lda. W: fp32, N x K row-major (converted in staging).
// bias/sym fp32. Output: bf16 to Cb, or fp32 to Cf if Cf != null.
__global__ __launch_bounds__(256) void gemm_tanh(
    const u16* __restrict__ A1, int lda1, const float* __restrict__ W1, int K1,
    const u16* __restrict__ A2, int lda2, const float* __restrict__ W2, int K2,
    const float* __restrict__ bias,
    const float* __restrict__ symS, const float* __restrict__ Sr, const float* __restrict__ sbr,
    u16* __restrict__ Cb, float* __restrict__ Cf, int N) {
  __shared__ u16 As[64][40];  // stride 40: max 2-way bank aliasing (free per m136)
  __shared__ u16 Bs[64][40];
  const int tid = threadIdx.x;
  const int lane = tid & 63, w = tid >> 6;
  const int wr = w >> 1, wc = w & 1;
  const int quad = lane >> 4, l16 = lane & 15;
  const int m0 = blockIdx.y * 64, n0 = blockIdx.x * 64;
  const int srow = tid >> 2, scol = (tid & 3) * 8;

  f32x4 acc[2][2];
#pragma unroll
  for (int i = 0; i < 2; ++i)
#pragma unroll
    for (int j = 0; j < 2; ++j) acc[i][j] = (f32x4){0.f, 0.f, 0.f, 0.f};

#pragma unroll
  for (int pair = 0; pair < 2; ++pair) {
    const u16* A = pair ? A2 : A1;
    const float* W = pair ? W2 : W1;
    const int lda = pair ? lda2 : lda1;
    const int K = pair ? K2 : K1;
    if (K == 0) continue;
    for (int k0 = 0; k0 < K; k0 += 32) {
      *(uint4*)&As[srow][scol] = *(const uint4*)&A[(long)(m0 + srow) * lda + k0 + scol];
      cvt8_to_lds(&W[(long)(n0 + srow) * K + k0 + scol], &Bs[srow][scol]);
      __syncthreads();
      bf16x8 af[2], bfr[2];
#pragma unroll
      for (int i = 0; i < 2; ++i)
        af[i] = *(const bf16x8*)&As[wr * 32 + i * 16 + l16][quad * 8];
#pragma unroll
      for (int j = 0; j < 2; ++j)
        bfr[j] = *(const bf16x8*)&Bs[wc * 32 + j * 16 + l16][quad * 8];
#pragma unroll
      for (int i = 0; i < 2; ++i)
#pragma unroll
        for (int j = 0; j < 2; ++j)
          acc[i][j] = __builtin_amdgcn_mfma_f32_16x16x32_bf16(af[i], bfr[j], acc[i][j], 0, 0, 0);
      __syncthreads();
    }
  }

#pragma unroll
  for (int j = 0; j < 2; ++j) {
    const int n = n0 + wc * 32 + j * 16 + l16;
    float bn = bias ? bias[n] : 0.0f;
    float srn[8];
    if (Sr) {
      bn += sbr[n];
#pragma unroll
      for (int q = 0; q < 8; ++q) srn[q] = Sr[n * 8 + q];
    }
#pragma unroll
    for (int i = 0; i < 2; ++i) {
#pragma unroll
      for (int r = 0; r < 4; ++r) {
        const int m = m0 + wr * 32 + i * 16 + quad * 4 + r;
        float v = acc[i][j][r] + bn;
        if (Sr) {
#pragma unroll
          for (int q = 0; q < 8; ++q) v += symS[(long)m * 128 + q] * srn[q];
        }
        v = tanhf(v);
        if (Cf) Cf[(long)m * N + n] = v;
        else Cb[(long)m * N + n] = f2bf(v);
      }
    }
  }
}

extern "C" void kernel_launch(void* const* d_in, const int* in_sizes, int n_in,
                              void* d_out, int out_size, void* d_ws, size_t ws_size,
                              hipStream_t stream) {
  // setup_inputs order; float tensors are fp32 (per reference dtypes)
  const float* inp = (const float*)d_in[0];   // (2048, 64, 12)
  const float* sym = (const float*)d_in[1];   // (2048, 16, 8)
  // d_in[2] = operations: compile-time-constant schedule, ignored
  const float* Wb  = (const float*)d_in[3];   // (512, 12)
  const float* bb  = (const float*)d_in[4];   // (512)
  const float* Wl  = (const float*)d_in[5];   // (1024, 512)
  const float* bl  = (const float*)d_in[6];   // (1024)
  const float* Wr  = (const float*)d_in[7];   // (1024, 512)
  const float* Ws  = (const float*)d_in[8];   // (512, 1024)
  const float* bs  = (const float*)d_in[9];   // (512)
  const float* Sl  = (const float*)d_in[10];  // (1024, 512)
  const float* sbl = (const float*)d_in[11];  // (1024)
  const float* Sr  = (const float*)d_in[12];  // (1024, 8)
  const float* sbr = (const float*)d_in[13];  // (1024)
  const float* Ss  = (const float*)d_in[14];  // (512, 1024)
  const float* sbs = (const float*)d_in[15];  // (512)

  const long B = 2048, NB = 64, F = 512, H = 1024;
  u16* ws = (u16*)d_ws;
  const size_t bigNeed = (size_t)(B * NB * F + B * H + B * F) * 2;

  dim3 blk(256);
  dim3 gH(H / 64, B / 64);  // (16, 32)
  dim3 gP(F / 64, B / 64);  // (8, 32)

  u16* accBuf;
  u16* hBuf;
  if (ws_size >= bigNeed) {
    // materialize all boxes: 134 MB bf16
    u16* boxes = ws;
    hBuf = boxes + B * NB * F;
    accBuf = hBuf + B * H;
    box_all_kernel<<<B * NB, 512, 0, stream>>>(inp, Wb, bb, boxes);
    const u16* curA = boxes + 63 * 512;
    int curLda = (int)(NB * F);
    for (int bp = 62; bp >= 0; --bp) {
      gemm_tanh<<<gH, blk, 0, stream>>>(curA, curLda, Wl, 512, boxes + bp * 512, (int)(NB * F),
                                        Wr, 512, bl, nullptr, nullptr, nullptr, hBuf, nullptr, 1024);
      gemm_tanh<<<gP, blk, 0, stream>>>(hBuf, 1024, Ws, 1024, nullptr, 0, nullptr, 0,
                                        bs, nullptr, nullptr, nullptr, accBuf, nullptr, 512);
      curA = accBuf;
      curLda = 512;
    }
  } else {
    // small-ws path (~10.5 MB): recompute box column per step
    u16* box63 = ws;
    u16* boxCur = box63 + B * F;
    hBuf = boxCur + B * F;
    accBuf = hBuf + B * H;
    box_one_kernel<<<B, 512, 0, stream>>>(inp, Wb, bb, 63, box63);
    const u16* curA = box63;
    int curLda = 512;
    for (int bp = 62; bp >= 0; --bp) {
      box_one_kernel<<<B, 512, 0, stream>>>(inp, Wb, bb, bp, boxCur);
      gemm_tanh<<<gH, blk, 0, stream>>>(curA, curLda, Wl, 512, boxCur, 512,
                                        Wr, 512, bl, nullptr, nullptr, nullptr, hBuf, nullptr, 1024);
      gemm_tanh<<<gP, blk, 0, stream>>>(hBuf, 1024, Ws, 1024, nullptr, 0, nullptr, 0,
                                        bs, nullptr, nullptr, nullptr, accBuf, nullptr, 512);
      curA = accBuf;
      curLda = 512;
    }
  }

  // 16 symmetry steps, symp = 15..0; final projection writes fp32 d_out
  for (int symp = 15; symp >= 0; --symp) {
    gemm_tanh<<<gH, blk, 0, stream>>>(accBuf, 512, Sl, 512, nullptr, 0, nullptr, 0,
                                      sbl, sym + symp * 8, Sr, sbr, hBuf, nullptr, 1024);
    float* dstF = (symp == 0) ? (float*)d_out : nullptr;
    gemm_tanh<<<gP, blk, 0, stream>>>(hBuf, 1024, Ss, 1024, nullptr, 0, nullptr, 0,
                                      sbs, nullptr, nullptr, nullptr, accBuf, dstF, 512);
  }
  (void)in_sizes; (void)n_in; (void)out_size;
}

// Round 3
// 2846.712 us; speedup vs baseline: 1.4258x; 1.4258x over previous
//
#include <hip/hip_runtime.h>
#include <cmath>

using u16 = unsigned short;
using u32 = unsigned int;
using bf16x8 = __attribute__((ext_vector_type(8))) __bf16;
using f32x4 = __attribute__((ext_vector_type(4))) float;

__device__ __forceinline__ u16 f2bf(float f) {
  union { float f; u32 i; } x; x.f = f;
  u32 r = x.i + 0x7FFFu + ((x.i >> 16) & 1u);
  return (u16)(r >> 16);
}
__device__ __forceinline__ float bf2f(u16 u) {
  union { u32 i; float f; } x; x.i = (u32)u << 16; return x.f;
}

// fp32 -> bf16 bulk convert, 8 elems/thread
__global__ void cvt_bf16(const float* __restrict__ src, u16* __restrict__ dst, int n) {
  int i = (blockIdx.x * 256 + threadIdx.x) * 8;
  if (i + 8 <= n) {
    float4 a = *(const float4*)(src + i), b = *(const float4*)(src + i + 4);
    u16 t[8] = {f2bf(a.x), f2bf(a.y), f2bf(a.z), f2bf(a.w),
                f2bf(b.x), f2bf(b.y), f2bf(b.z), f2bf(b.w)};
    *(uint4*)(dst + i) = *(uint4*)t;
  }
}

// boxes[b][i][f] = tanh(inp[b][i]@Wb^T + bb), one block per b, Wb rows in registers
__global__ __launch_bounds__(256) void box_all_v2(const float* __restrict__ inp,
    const float* __restrict__ Wb, const float* __restrict__ bb, u16* __restrict__ boxes) {
  int b = blockIdx.x, t = threadIdx.x;
  __shared__ float sin_[64][12];
  for (int idx = t; idx < 768; idx += 256) sin_[idx / 12][idx % 12] = inp[(long)b * 768 + idx];
  const int f0 = t * 2;
  float w0[12], w1[12];
#pragma unroll
  for (int q = 0; q < 12; ++q) { w0[q] = Wb[f0 * 12 + q]; w1[q] = Wb[(f0 + 1) * 12 + q]; }
  float b0 = bb[f0], b1 = bb[f0 + 1];
  __syncthreads();
  for (int i = 0; i < 64; ++i) {
    float a0 = b0, a1 = b1;
#pragma unroll
    for (int q = 0; q < 12; ++q) { float x = sin_[i][q]; a0 += x * w0[q]; a1 += x * w1[q]; }
    u32 pk = (u32)f2bf(tanhf(a0)) | ((u32)f2bf(tanhf(a1)) << 16);
    *(u32*)&boxes[(((long)b * 64 + i) * 512) + f0] = pk;
  }
}

// fallback: single box column bp (small-ws path)
__global__ void box_one_kernel(const float* __restrict__ inp, const float* __restrict__ Wb,
                               const float* __restrict__ bb, int bp, u16* __restrict__ outBox) {
  int b = blockIdx.x;
  int f = threadIdx.x;
  __shared__ float s_in[12];
  if (f < 12) s_in[f] = inp[((long)b * 64 + bp) * 12 + f];
  __syncthreads();
  float a = bb[f];
#pragma unroll
  for (int q = 0; q < 12; ++q) a += s_in[q] * Wb[f * 12 + q];
  outBox[(long)b * 512 + f] = f2bf(tanhf(a));
}

// C = act( A1@W1^T (+ A2@W2^T) + bias + Radd + sym ),  BK=64, 64x64 tile, 4 waves.
// A bf16 (M x K, row stride lda). W either bf16 (Wb) or fp32 (Wf, converted in staging).
// outMode: 0 = bf16 Cb[m*N+n], 1 = fp32 Cf[m*N+n], 2 = R-scatter Cb[(m&63)*ldRout+(m>>6)*N+n], skip m&63==63
__global__ __launch_bounds__(256) void gemm64(
    const u16* __restrict__ A1, int lda1,
    const u16* __restrict__ W1b, const float* __restrict__ W1f, int K1,
    const u16* __restrict__ A2, int lda2,
    const u16* __restrict__ W2b, const float* __restrict__ W2f, int K2,
    const float* __restrict__ bias,
    const u16* __restrict__ Radd, long ldr,
    const float* __restrict__ symS, const float* __restrict__ Srw, const float* __restrict__ sbr,
    int doTanh, int outMode, long ldRout,
    u16* __restrict__ Cb, float* __restrict__ Cf, int N) {
  __shared__ u16 As[64][72];  // stride 72 elems = 144 B: 16B-aligned rows, 2-way bank aliasing (free)
  __shared__ u16 Bs[64][72];
  const int tid = threadIdx.x;
  const int lane = tid & 63, w = tid >> 6;
  const int wr = w >> 1, wc = w & 1;
  const int quad = lane >> 4, l16 = lane & 15;
  const int m0 = blockIdx.y * 64, n0 = blockIdx.x * 64;
  const int srow = tid >> 2, scol = (tid & 3) * 16;

  f32x4 acc[2][2];
#pragma unroll
  for (int i = 0; i < 2; ++i)
#pragma unroll
    for (int j = 0; j < 2; ++j) acc[i][j] = (f32x4){0.f, 0.f, 0.f, 0.f};

#pragma unroll
  for (int pair = 0; pair < 2; ++pair) {
    const u16* A = pair ? A2 : A1;
    const u16* Wb_ = pair ? W2b : W1b;
    const float* Wf_ = pair ? W2f : W1f;
    const int lda = pair ? lda2 : lda1;
    const int K = pair ? K2 : K1;
    if (K == 0) continue;
    for (int k0 = 0; k0 < K; k0 += 64) {
      // global loads to regs first (latency overlaps the barrier)
      const u16* ap = &A[(long)(m0 + srow) * lda + k0 + scol];
      uint4 av0 = *(const uint4*)ap;
      uint4 av1 = *(const uint4*)(ap + 8);
      uint4 bv0, bv1;
      if (Wb_) {
        const u16* wp = &Wb_[(long)(n0 + srow) * K + k0 + scol];
        bv0 = *(const uint4*)wp;
        bv1 = *(const uint4*)(wp + 8);
      } else {
        const float* wp = &Wf_[(long)(n0 + srow) * K + k0 + scol];
        u16 t[16];
#pragma unroll
        for (int q = 0; q < 16; ++q) t[q] = f2bf(wp[q]);
        bv0 = ((uint4*)t)[0];
        bv1 = ((uint4*)t)[1];
      }
      __syncthreads();  // protect previous iter's fragment reads
      *(uint4*)&As[srow][scol] = av0;
      *(uint4*)&As[srow][scol + 8] = av1;
      *(uint4*)&Bs[srow][scol] = bv0;
      *(uint4*)&Bs[srow][scol + 8] = bv1;
      __syncthreads();
      bf16x8 af[2][2], bfv[2][2];
#pragma unroll
      for (int kk = 0; kk < 2; ++kk) {
#pragma unroll
        for (int i = 0; i < 2; ++i)
          af[i][kk] = *(const bf16x8*)&As[wr * 32 + i * 16 + l16][kk * 32 + quad * 8];
#pragma unroll
        for (int j = 0; j < 2; ++j)
          bfv[j][kk] = *(const bf16x8*)&Bs[wc * 32 + j * 16 + l16][kk * 32 + quad * 8];
      }
#pragma unroll
      for (int kk = 0; kk < 2; ++kk)
#pragma unroll
        for (int i = 0; i < 2; ++i)
#pragma unroll
          for (int j = 0; j < 2; ++j)
            acc[i][j] = __builtin_amdgcn_mfma_f32_16x16x32_bf16(af[i][kk], bfv[j][kk], acc[i][j], 0, 0, 0);
    }
  }

#pragma unroll
  for (int j = 0; j < 2; ++j) {
    const int n = n0 + wc * 32 + j * 16 + l16;
    float bn = bias ? bias[n] : 0.0f;
    float srn[8];
    if (symS) {
      bn += sbr[n];
#pragma unroll
      for (int q = 0; q < 8; ++q) srn[q] = Srw[n * 8 + q];
    }
#pragma unroll
    for (int i = 0; i < 2; ++i) {
#pragma unroll
      for (int r = 0; r < 4; ++r) {
        const int m = m0 + wr * 32 + i * 16 + quad * 4 + r;
        float v = acc[i][j][r] + bn;
        if (Radd) v += bf2f(Radd[(long)m * ldr + n]);
        if (symS) {
#pragma unroll
          for (int q = 0; q < 8; ++q) v += symS[(long)m * 128 + q] * srn[q];
        }
        if (doTanh) v = tanhf(v);
        if (outMode == 0) Cb[(long)m * N + n] = f2bf(v);
        else if (outMode == 1) Cf[(long)m * N + n] = v;
        else {
          int ii = m & 63;
          if (ii != 63) Cb[(long)ii * ldRout + (long)(m >> 6) * N + n] = f2bf(v);
        }
      }
    }
  }
}

extern "C" void kernel_launch(void* const* d_in, const int* in_sizes, int n_in,
                              void* d_out, int out_size, void* d_ws, size_t ws_size,
                              hipStream_t stream) {
  const float* inp = (const float*)d_in[0];   // (2048, 64, 12)
  const float* sym = (const float*)d_in[1];   // (2048, 16, 8)
  const float* Wb  = (const float*)d_in[3];   // (512, 12)
  const float* bb  = (const float*)d_in[4];   // (512)
  const float* Wl  = (const float*)d_in[5];   // (1024, 512)
  const float* bl  = (const float*)d_in[6];   // (1024)
  const float* Wr  = (const float*)d_in[7];   // (1024, 512)
  const float* Ws  = (const float*)d_in[8];   // (512, 1024)
  const float* bs  = (const float*)d_in[9];   // (512)
  const float* Sl  = (const float*)d_in[10];  // (1024, 512)
  const float* sbl = (const float*)d_in[11];  // (1024)
  const float* Sr  = (const float*)d_in[12];  // (1024, 8)
  const float* sbr = (const float*)d_in[13];  // (1024)
  const float* Ss  = (const float*)d_in[14];  // (512, 1024)
  const float* sbs = (const float*)d_in[15];  // (512)

  const long B = 2048, NB = 64, F = 512, H = 1024;
  const long WE = 524288;  // elems per weight matrix (both 1024x512 and 512x1024)
  u16* ws = (u16*)d_ws;

  const size_t szW = 5 * WE * 2, szBoxes = (size_t)B * NB * F * 2, szR = (size_t)63 * B * H * 2;
  const size_t szH = (size_t)B * H * 2, szAcc = (size_t)B * F * 2;
  const size_t needT1 = szW + szBoxes + szR + szH + szAcc;   // ~410 MB
  const size_t needT2 = szW + szBoxes + szH + szAcc;         // ~146 MB
  const size_t needT3 = szBoxes + szH + szAcc;               // ~140.5 MB
  int tier = (ws_size >= needT1) ? 1 : (ws_size >= needT2) ? 2 : (ws_size >= needT3) ? 3 : 4;

  dim3 blk(256);
  dim3 gH(16, 32), gP(8, 32), gR(16, 2048);

  // bf16 weight pointers (tier 1/2); fp32 fallbacks otherwise
  u16 *WlB = nullptr, *WrB = nullptr, *WsB = nullptr, *SlB = nullptr, *SsB = nullptr;
  const float *WlF = Wl, *WrF = Wr, *WsF = Ws, *SlF = Sl, *SsF = Ss;
  u16* p = ws;
  if (tier <= 2) {
    WlB = p; WrB = p + WE; WsB = p + 2 * WE; SlB = p + 3 * WE; SsB = p + 4 * WE;
    p += 5 * WE;
    cvt_bf16<<<WE / 2048, blk, 0, stream>>>(Wl, WlB, (int)WE);
    cvt_bf16<<<WE / 2048, blk, 0, stream>>>(Wr, WrB, (int)WE);
    cvt_bf16<<<WE / 2048, blk, 0, stream>>>(Ws, WsB, (int)WE);
    cvt_bf16<<<WE / 2048, blk, 0, stream>>>(Sl, SlB, (int)WE);
    cvt_bf16<<<WE / 2048, blk, 0, stream>>>(Ss, SsB, (int)WE);
    WlF = WrF = WsF = SlF = SsF = nullptr;
  }

  u16 *accBuf, *hBuf;
  if (tier <= 3) {
    u16* boxes = p;
    p += B * NB * F;
    u16* Rbuf = nullptr;
    if (tier == 1) { Rbuf = p; p += 63 * B * H; }
    hBuf = p; p += B * H;
    accBuf = p;
    box_all_v2<<<B, blk, 0, stream>>>(inp, Wb, bb, boxes);
    if (tier == 1) {
      // R[i][b][:] = boxes[b][i] @ Wr^T for i<63 — one big parallel GEMM
      gemm64<<<gR, blk, 0, stream>>>(boxes, 512, WrB, WrF, 512,
                                     nullptr, 0, nullptr, nullptr, 0,
                                     nullptr, nullptr, 0, nullptr, nullptr, nullptr,
                                     0, 2, B * H, Rbuf, nullptr, 1024);
    }
    const u16* curA = boxes + 63 * 512;
    int curLda = (int)(NB * F);
    for (int bp = 62; bp >= 0; --bp) {
      if (tier == 1) {
        gemm64<<<gH, blk, 0, stream>>>(curA, curLda, WlB, WlF, 512,
                                       nullptr, 0, nullptr, nullptr, 0,
                                       bl, Rbuf + (long)bp * B * H, 1024,
                                       nullptr, nullptr, nullptr, 1, 0, 0, hBuf, nullptr, 1024);
      } else {
        gemm64<<<gH, blk, 0, stream>>>(curA, curLda, WlB, WlF, 512,
                                       boxes + (long)bp * 512, (int)(NB * F), WrB, WrF, 512,
                                       bl, nullptr, 0, nullptr, nullptr, nullptr,
                                       1, 0, 0, hBuf, nullptr, 1024);
      }
      gemm64<<<gP, blk, 0, stream>>>(hBuf, 1024, WsB, WsF, 1024,
                                     nullptr, 0, nullptr, nullptr, 0,
                                     bs, nullptr, 0, nullptr, nullptr, nullptr,
                                     1, 0, 0, accBuf, nullptr, 512);
      curA = accBuf;
      curLda = 512;
    }
  } else {
    // tiny-ws path
    u16* box63 = ws;
    u16* boxCur = box63 + B * F;
    hBuf = boxCur + B * F;
    accBuf = hBuf + B * H;
    box_one_kernel<<<B, 512, 0, stream>>>(inp, Wb, bb, 63, box63);
    const u16* curA = box63;
    int curLda = 512;
    for (int bp = 62; bp >= 0; --bp) {
      box_one_kernel<<<B, 512, 0, stream>>>(inp, Wb, bb, bp, boxCur);
      gemm64<<<gH, blk, 0, stream>>>(curA, curLda, nullptr, Wl, 512,
                                     boxCur, 512, nullptr, Wr, 512,
                                     bl, nullptr, 0, nullptr, nullptr, nullptr,
                                     1, 0, 0, hBuf, nullptr, 1024);
      gemm64<<<gP, blk, 0, stream>>>(hBuf, 1024, nullptr, Ws, 1024,
                                     nullptr, 0, nullptr, nullptr, 0,
                                     bs, nullptr, 0, nullptr, nullptr, nullptr,
                                     1, 0, 0, accBuf, nullptr, 512);
      curA = accBuf;
      curLda = 512;
    }
  }

  // 16 symmetry steps; final projection writes fp32 d_out
  for (int symp = 15; symp >= 0; --symp) {
    gemm64<<<gH, blk, 0, stream>>>(accBuf, 512, SlB, SlF, 512,
                                   nullptr, 0, nullptr, nullptr, 0,
                                   sbl, nullptr, 0, sym + symp * 8, Sr, sbr,
                                   1, 0, 0, hBuf, nullptr, 1024);
    int om = (symp == 0) ? 1 : 0;
    gemm64<<<gP, blk, 0, stream>>>(hBuf, 1024, SsB, SsF, 1024,
                                   nullptr, 0, nullptr, nullptr, 0,
                                   sbs, nullptr, 0, nullptr, nullptr, nullptr,
                                   1, om, 0, accBuf, (float*)d_out, 512);
  }
  (void)in_sizes; (void)n_in; (void)out_size;
}

// Round 4
// 2444.416 us; speedup vs baseline: 1.6604x; 1.1646x over previous
//
#include <hip/hip_runtime.h>
#include <cmath>

using u16 = unsigned short;
using u32 = unsigned int;
using bf16x8 = __attribute__((ext_vector_type(8))) __bf16;
using f32x4 = __attribute__((ext_vector_type(4))) float;

__device__ __forceinline__ u16 f2bf(float f) {
  union { float f; u32 i; } x; x.f = f;
  u32 r = x.i + 0x7FFFu + ((x.i >> 16) & 1u);
  return (u16)(r >> 16);
}
__device__ __forceinline__ float bf2f(u16 u) {
  union { u32 i; float f; } x; x.i = (u32)u << 16; return x.f;
}
__device__ __forceinline__ float fast_tanh(float x) {
  float e = __expf(2.0f * x);
  return 1.0f - 2.0f / (e + 1.0f);
}
__device__ __forceinline__ void load_lds16(const u16* g, u16* l) {
  __builtin_amdgcn_global_load_lds((const __attribute__((address_space(1))) u32*)g,
                                   (__attribute__((address_space(3))) u32*)l, 16, 0, 0);
}

// ---------------- fp32 -> bf16 bulk convert ----------------
__global__ void cvt_bf16(const float* __restrict__ src, u16* __restrict__ dst, int n) {
  int i = (blockIdx.x * 256 + threadIdx.x) * 8;
  if (i + 8 <= n) {
    float4 a = *(const float4*)(src + i), b = *(const float4*)(src + i + 4);
    u16 t[8] = {f2bf(a.x), f2bf(a.y), f2bf(a.z), f2bf(a.w),
                f2bf(b.x), f2bf(b.y), f2bf(b.z), f2bf(b.w)};
    *(uint4*)(dst + i) = *(uint4*)t;
  }
}

// ---------------- boxesT[i][b][f] = tanh(inp[b][i]@Wb^T + bb) ----------------
__global__ __launch_bounds__(256) void box_allT(const float* __restrict__ inp,
    const float* __restrict__ Wb, const float* __restrict__ bb, u16* __restrict__ boxesT) {
  int b = blockIdx.x, t = threadIdx.x;
  __shared__ float sin_[64][12];
  for (int idx = t; idx < 768; idx += 256) sin_[idx / 12][idx % 12] = inp[(long)b * 768 + idx];
  int f0 = (t & 127) * 4, hf = t >> 7;
  float w[4][12], bz[4];
#pragma unroll
  for (int r = 0; r < 4; ++r) {
    bz[r] = bb[f0 + r];
#pragma unroll
    for (int q = 0; q < 12; ++q) w[r][q] = Wb[(f0 + r) * 12 + q];
  }
  __syncthreads();
  for (int i = hf; i < 64; i += 2) {
    float a[4] = {bz[0], bz[1], bz[2], bz[3]};
#pragma unroll
    for (int q = 0; q < 12; ++q) {
      float x = sin_[i][q];
#pragma unroll
      for (int r = 0; r < 4; ++r) a[r] += x * w[r][q];
    }
    u16 p[4];
#pragma unroll
    for (int r = 0; r < 4; ++r) p[r] = f2bf(fast_tanh(a[r]));
    *(uint2*)&boxesT[((long)i * 2048 + b) * 512 + f0] = *(uint2*)p;
  }
}

// ---------------- R = boxesT(0..62) @ Wr^T : 128x128 tile, BK=32, m97-style ----------------
__global__ __launch_bounds__(256, 2) void gemm_R(const u16* __restrict__ A,
                                                 const u16* __restrict__ W,
                                                 u16* __restrict__ R) {
  __shared__ u16 smem[8192];  // As = [0..4095] (128x32), Bs = [4096..]; reused for epilogue staging
  const int tid = threadIdx.x, lane = tid & 63, w = tid >> 6;
  const int wr = w >> 1, wc = w & 1, q = lane >> 4, l16 = lane & 15;
  const long m0 = (long)blockIdx.y * 128;
  const int n0 = blockIdx.x * 128;
  f32x4 C[4][4];
#pragma unroll
  for (int i = 0; i < 4; ++i)
#pragma unroll
    for (int j = 0; j < 4; ++j) C[i][j] = (f32x4){0.f, 0.f, 0.f, 0.f};

  for (int k0 = 0; k0 < 512; k0 += 32) {
    __syncthreads();
#pragma unroll
    for (int jj = 0; jj < 2; ++jj) {
      int c = jj * 256 + w * 64;
      int ch = c + lane;
      load_lds16(&A[(m0 + (ch >> 2)) * 512 + k0 + (ch & 3) * 8], &smem[0] + c * 8);
      load_lds16(&W[((long)(n0 + (ch >> 2))) * 512 + k0 + (ch & 3) * 8], &smem[4096] + c * 8);
    }
    __syncthreads();
    bf16x8 af[4], bfv[4];
#pragma unroll
    for (int i = 0; i < 4; ++i) af[i] = *(const bf16x8*)&smem[(wr * 64 + i * 16 + l16) * 32 + q * 8];
#pragma unroll
    for (int j = 0; j < 4; ++j) bfv[j] = *(const bf16x8*)&smem[4096 + (wc * 64 + j * 16 + l16) * 32 + q * 8];
#pragma unroll
    for (int i = 0; i < 4; ++i)
#pragma unroll
      for (int j = 0; j < 4; ++j)
        C[i][j] = __builtin_amdgcn_mfma_f32_16x16x32_bf16(af[i], bfv[j], C[i][j], 0, 0, 0);
  }
  // epilogue: restage through LDS for coalesced 64B stores
  for (int hv = 0; hv < 2; ++hv) {
    __syncthreads();
    if (wc == hv) {
#pragma unroll
      for (int i = 0; i < 4; ++i)
#pragma unroll
        for (int j = 0; j < 4; ++j)
#pragma unroll
          for (int r = 0; r < 4; ++r)
            smem[(wr * 64 + i * 16 + q * 4 + r) * 64 + j * 16 + l16] = f2bf(C[i][j][r]);
    }
    __syncthreads();
    u16* dst = R + (m0 + (tid >> 1)) * 1024 + n0 + hv * 64 + (tid & 1) * 32;
    const u16* s = &smem[(tid >> 1) * 64 + (tid & 1) * 32];
#pragma unroll
    for (int v = 0; v < 4; ++v) ((uint4*)dst)[v] = ((const uint4*)s)[v];
  }
}

// ---------------- the whole sequential chain: 63 left-steps + 16 sym-steps ----------------
// 128 blocks x 16 rows; acc/h in LDS; weight B-frags streamed from L2.
__global__ __launch_bounds__(256, 1) void chain_kernel(
    const u16* __restrict__ boxesT, const u16* __restrict__ Rbuf,
    const u16* __restrict__ Wl, const u16* __restrict__ Ws,
    const u16* __restrict__ Sl, const u16* __restrict__ Ss,
    const float* __restrict__ bl, const float* __restrict__ bs,
    const float* __restrict__ sbl, const float* __restrict__ sbr,
    const float* __restrict__ sbs, const float* __restrict__ SrF,
    const float* __restrict__ sym, float* __restrict__ outF) {
  __shared__ u16 sA[16][520];   // acc (A operand, K=512), padded
  __shared__ u16 sH[16][1032];  // h   (A operand, K=1024), padded
  __shared__ float sSym[16][8];

  const int tid = threadIdx.x, lane = tid & 63, w = tid >> 6;
  const int q = lane >> 4, l16 = lane & 15;
  const int m0 = blockIdx.x * 16;

  // init acc <- boxesT[63]
  {
    const u16* src = boxesT + ((long)63 * 2048 + m0) * 512;
    int o = tid * 32, r = o >> 9, c = o & 511;
#pragma unroll
    for (int v = 0; v < 4; ++v)
      *(uint4*)&sA[r][c + v * 8] = *(const uint4*)&src[(long)r * 512 + c + v * 8];
  }
  __syncthreads();

  for (int t = 0; t < 79; ++t) {
    const bool symPhase = (t >= 63);
    const int bp = 62 - t;  // valid for chain steps
    if (symPhase) {
      int symp = 15 - (t - 63);
      if (tid < 128) sSym[tid >> 3][tid & 7] = sym[((long)(m0 + (tid >> 3)) * 16 + symp) * 8 + (tid & 7)];
      __syncthreads();
    }
    // ---- LEFT: h = tanh(acc @ WL^T + bias (+R | +sym@Sr^T)) ----
    const u16* WL = symPhase ? Sl : Wl;
    // R register prefetch (chain steps): 64 scalar u16 loads, issued early
    u16 rv0[8][4], rv1[8][4];
    if (!symPhase) {
      const u16* rbase = Rbuf + ((long)bp * 2048 + m0) * 1024;
#pragma unroll
      for (int np = 0; np < 8; ++np) {
        int nb = w * 256 + np * 32 + l16;
#pragma unroll
        for (int r = 0; r < 4; ++r) {
          rv0[np][r] = rbase[(long)(q * 4 + r) * 1024 + nb];
          rv1[np][r] = rbase[(long)(q * 4 + r) * 1024 + nb + 16];
        }
      }
    }
    bf16x8 Af[16];
#pragma unroll
    for (int s = 0; s < 16; ++s) Af[s] = *(const bf16x8*)&sA[l16][s * 32 + q * 8];
    float symv[4][8];
    if (symPhase) {
#pragma unroll
      for (int r = 0; r < 4; ++r)
#pragma unroll
        for (int k = 0; k < 8; ++k) symv[r][k] = sSym[q * 4 + r][k];
    }
    for (int np = 0; np < 8; ++np) {
      int n0 = w * 256 + np * 32;
      f32x4 C0 = {0.f, 0.f, 0.f, 0.f}, C1 = {0.f, 0.f, 0.f, 0.f};
      const u16* w0 = WL + (long)(n0 + l16) * 512 + q * 8;
      const u16* w1 = w0 + 16 * 512;
#pragma unroll 8
      for (int s = 0; s < 16; ++s) {
        bf16x8 b0 = *(const bf16x8*)(w0 + s * 32);
        bf16x8 b1 = *(const bf16x8*)(w1 + s * 32);
        C0 = __builtin_amdgcn_mfma_f32_16x16x32_bf16(Af[s], b0, C0, 0, 0, 0);
        C1 = __builtin_amdgcn_mfma_f32_16x16x32_bf16(Af[s], b1, C1, 0, 0, 0);
      }
      int n0b = n0 + l16, n1b = n0 + 16 + l16;
      float bn0, bn1, sr0[8], sr1[8];
      if (!symPhase) { bn0 = bl[n0b]; bn1 = bl[n1b]; }
      else {
        bn0 = sbl[n0b] + sbr[n0b]; bn1 = sbl[n1b] + sbr[n1b];
        *(float4*)&sr0[0] = *(const float4*)&SrF[(long)n0b * 8];
        *(float4*)&sr0[4] = *(const float4*)&SrF[(long)n0b * 8 + 4];
        *(float4*)&sr1[0] = *(const float4*)&SrF[(long)n1b * 8];
        *(float4*)&sr1[4] = *(const float4*)&SrF[(long)n1b * 8 + 4];
      }
#pragma unroll
      for (int r = 0; r < 4; ++r) {
        int m = q * 4 + r;
        float v0 = C0[r] + bn0;
        float v1 = C1[r] + bn1;
        if (!symPhase) { v0 += bf2f(rv0[np][r]); v1 += bf2f(rv1[np][r]); }
        else {
#pragma unroll
          for (int k = 0; k < 8; ++k) { v0 += symv[r][k] * sr0[k]; v1 += symv[r][k] * sr1[k]; }
        }
        sH[m][n0b] = f2bf(fast_tanh(v0));
        sH[m][n1b] = f2bf(fast_tanh(v1));
      }
    }
    __syncthreads();
    // ---- PROJ: acc' = tanh(h @ WP^T + bias) ----
    const u16* WP = symPhase ? Ss : Ws;
    const float* b2 = symPhase ? sbs : bs;
    bf16x8 Hf[32];
#pragma unroll
    for (int s = 0; s < 32; ++s) Hf[s] = *(const bf16x8*)&sH[l16][s * 32 + q * 8];
    const bool last = (t == 78);
    for (int fp = 0; fp < 4; ++fp) {
      int f0 = w * 128 + fp * 32;
      f32x4 C0 = {0.f, 0.f, 0.f, 0.f}, C1 = {0.f, 0.f, 0.f, 0.f};
      const u16* w0 = WP + (long)(f0 + l16) * 1024 + q * 8;
      const u16* w1 = w0 + 16 * 1024;
#pragma unroll 8
      for (int s = 0; s < 32; ++s) {
        bf16x8 b0 = *(const bf16x8*)(w0 + s * 32);
        bf16x8 b1 = *(const bf16x8*)(w1 + s * 32);
        C0 = __builtin_amdgcn_mfma_f32_16x16x32_bf16(Hf[s], b0, C0, 0, 0, 0);
        C1 = __builtin_amdgcn_mfma_f32_16x16x32_bf16(Hf[s], b1, C1, 0, 0, 0);
      }
      int f0b = f0 + l16, f1b = f0 + 16 + l16;
      float bn0 = b2[f0b], bn1 = b2[f1b];
#pragma unroll
      for (int r = 0; r < 4; ++r) {
        int m = q * 4 + r;
        float a0 = fast_tanh(C0[r] + bn0);
        float a1 = fast_tanh(C1[r] + bn1);
        sA[m][f0b] = f2bf(a0);
        sA[m][f1b] = f2bf(a1);
        if (last) {
          outF[(long)(m0 + m) * 512 + f0b] = a0;
          outF[(long)(m0 + m) * 512 + f1b] = a1;
        }
      }
    }
    __syncthreads();
  }
}

// ================= fallback kernels (small-ws path, round-3 logic) =================
__global__ __launch_bounds__(256) void box_all_v2(const float* __restrict__ inp,
    const float* __restrict__ Wb, const float* __restrict__ bb, u16* __restrict__ boxes) {
  int b = blockIdx.x, t = threadIdx.x;
  __shared__ float sin_[64][12];
  for (int idx = t; idx < 768; idx += 256) sin_[idx / 12][idx % 12] = inp[(long)b * 768 + idx];
  const int f0 = t * 2;
  float w0[12], w1[12];
#pragma unroll
  for (int q = 0; q < 12; ++q) { w0[q] = Wb[f0 * 12 + q]; w1[q] = Wb[(f0 + 1) * 12 + q]; }
  float b0 = bb[f0], b1 = bb[f0 + 1];
  __syncthreads();
  for (int i = 0; i < 64; ++i) {
    float a0 = b0, a1 = b1;
#pragma unroll
    for (int q = 0; q < 12; ++q) { float x = sin_[i][q]; a0 += x * w0[q]; a1 += x * w1[q]; }
    u32 pk = (u32)f2bf(fast_tanh(a0)) | ((u32)f2bf(fast_tanh(a1)) << 16);
    *(u32*)&boxes[(((long)b * 64 + i) * 512) + f0] = pk;
  }
}

__global__ __launch_bounds__(256) void gemm64(
    const u16* __restrict__ A1, int lda1,
    const u16* __restrict__ W1b, const float* __restrict__ W1f, int K1,
    const u16* __restrict__ A2, int lda2,
    const u16* __restrict__ W2b, const float* __restrict__ W2f, int K2,
    const float* __restrict__ bias,
    const float* __restrict__ symS, const float* __restrict__ Srw, const float* __restrict__ sbr,
    int doTanh, int outMode,
    u16* __restrict__ Cb, float* __restrict__ Cf, int N) {
  __shared__ u16 As[64][72];
  __shared__ u16 Bs[64][72];
  const int tid = threadIdx.x;
  const int lane = tid & 63, w = tid >> 6;
  const int wr = w >> 1, wc = w & 1;
  const int quad = lane >> 4, l16 = lane & 15;
  const int m0 = blockIdx.y * 64, n0 = blockIdx.x * 64;
  const int srow = tid >> 2, scol = (tid & 3) * 16;
  f32x4 acc[2][2];
#pragma unroll
  for (int i = 0; i < 2; ++i)
#pragma unroll
    for (int j = 0; j < 2; ++j) acc[i][j] = (f32x4){0.f, 0.f, 0.f, 0.f};
#pragma unroll
  for (int pair = 0; pair < 2; ++pair) {
    const u16* A = pair ? A2 : A1;
    const u16* Wb_ = pair ? W2b : W1b;
    const float* Wf_ = pair ? W2f : W1f;
    const int lda = pair ? lda2 : lda1;
    const int K = pair ? K2 : K1;
    if (K == 0) continue;
    for (int k0 = 0; k0 < K; k0 += 64) {
      const u16* ap = &A[(long)(m0 + srow) * lda + k0 + scol];
      uint4 av0 = *(const uint4*)ap;
      uint4 av1 = *(const uint4*)(ap + 8);
      uint4 bv0, bv1;
      if (Wb_) {
        const u16* wp = &Wb_[(long)(n0 + srow) * K + k0 + scol];
        bv0 = *(const uint4*)wp;
        bv1 = *(const uint4*)(wp + 8);
      } else {
        const float* wp = &Wf_[(long)(n0 + srow) * K + k0 + scol];
        u16 tv[16];
#pragma unroll
        for (int qq = 0; qq < 16; ++qq) tv[qq] = f2bf(wp[qq]);
        bv0 = ((uint4*)tv)[0];
        bv1 = ((uint4*)tv)[1];
      }
      __syncthreads();
      *(uint4*)&As[srow][scol] = av0;
      *(uint4*)&As[srow][scol + 8] = av1;
      *(uint4*)&Bs[srow][scol] = bv0;
      *(uint4*)&Bs[srow][scol + 8] = bv1;
      __syncthreads();
      bf16x8 af[2][2], bfv[2][2];
#pragma unroll
      for (int kk = 0; kk < 2; ++kk) {
#pragma unroll
        for (int i = 0; i < 2; ++i)
          af[i][kk] = *(const bf16x8*)&As[wr * 32 + i * 16 + l16][kk * 32 + quad * 8];
#pragma unroll
        for (int j = 0; j < 2; ++j)
          bfv[j][kk] = *(const bf16x8*)&Bs[wc * 32 + j * 16 + l16][kk * 32 + quad * 8];
      }
#pragma unroll
      for (int kk = 0; kk < 2; ++kk)
#pragma unroll
        for (int i = 0; i < 2; ++i)
#pragma unroll
          for (int j = 0; j < 2; ++j)
            acc[i][j] = __builtin_amdgcn_mfma_f32_16x16x32_bf16(af[i][kk], bfv[j][kk], acc[i][j], 0, 0, 0);
    }
  }
#pragma unroll
  for (int j = 0; j < 2; ++j) {
    const int n = n0 + wc * 32 + j * 16 + l16;
    float bn = bias ? bias[n] : 0.0f;
    float srn[8];
    if (symS) {
      bn += sbr[n];
#pragma unroll
      for (int qq = 0; qq < 8; ++qq) srn[qq] = Srw[n * 8 + qq];
    }
#pragma unroll
    for (int i = 0; i < 2; ++i) {
#pragma unroll
      for (int r = 0; r < 4; ++r) {
        const int m = m0 + wr * 32 + i * 16 + quad * 4 + r;
        float v = acc[i][j][r] + bn;
        if (symS) {
#pragma unroll
          for (int qq = 0; qq < 8; ++qq) v += symS[(long)m * 128 + qq] * srn[qq];
        }
        if (doTanh) v = fast_tanh(v);
        if (outMode == 0) Cb[(long)m * N + n] = f2bf(v);
        else Cf[(long)m * N + n] = v;
      }
    }
  }
}

extern "C" void kernel_launch(void* const* d_in, const int* in_sizes, int n_in,
                              void* d_out, int out_size, void* d_ws, size_t ws_size,
                              hipStream_t stream) {
  const float* inp = (const float*)d_in[0];
  const float* sym = (const float*)d_in[1];
  const float* Wb  = (const float*)d_in[3];
  const float* bb  = (const float*)d_in[4];
  const float* Wl  = (const float*)d_in[5];
  const float* bl  = (const float*)d_in[6];
  const float* Wr  = (const float*)d_in[7];
  const float* Ws  = (const float*)d_in[8];
  const float* bs  = (const float*)d_in[9];
  const float* Sl  = (const float*)d_in[10];
  const float* sbl = (const float*)d_in[11];
  const float* Sr  = (const float*)d_in[12];
  const float* sbr = (const float*)d_in[13];
  const float* Ss  = (const float*)d_in[14];
  const float* sbs = (const float*)d_in[15];

  const long B = 2048, NB = 64, F = 512, H = 1024;
  const long WE = 524288;
  u16* ws = (u16*)d_ws;
  dim3 blk(256);

  const size_t needNew = ((size_t)5 * WE + (size_t)64 * B * F + (size_t)63 * B * H) * 2;  // ~404 MB

  if (ws_size >= needNew) {
    u16* WlB = ws;
    u16* WrB = WlB + WE;
    u16* WsB = WrB + WE;
    u16* SlB = WsB + WE;
    u16* SsB = SlB + WE;
    u16* boxesT = SsB + WE;                  // [64][2048][512]
    u16* Rbuf = boxesT + 64 * B * F;         // [63][2048][1024]

    cvt_bf16<<<WE / 2048, blk, 0, stream>>>(Wl, WlB, (int)WE);
    cvt_bf16<<<WE / 2048, blk, 0, stream>>>(Wr, WrB, (int)WE);
    cvt_bf16<<<WE / 2048, blk, 0, stream>>>(Ws, WsB, (int)WE);
    cvt_bf16<<<WE / 2048, blk, 0, stream>>>(Sl, SlB, (int)WE);
    cvt_bf16<<<WE / 2048, blk, 0, stream>>>(Ss, SsB, (int)WE);
    box_allT<<<B, blk, 0, stream>>>(inp, Wb, bb, boxesT);
    gemm_R<<<dim3(8, 1008), blk, 0, stream>>>(boxesT, WrB, Rbuf);
    chain_kernel<<<128, blk, 0, stream>>>(boxesT, Rbuf, WlB, WsB, SlB, SsB,
                                          bl, bs, sbl, sbr, sbs, Sr, sym, (float*)d_out);
  } else {
    // fallback: round-3 tier-2-style path (bf16 weights if they fit, else fp32 staging)
    dim3 gH(16, 32), gP(8, 32);
    const size_t szW = 5 * WE * 2, szBoxes = (size_t)B * NB * F * 2;
    const size_t szH = (size_t)B * H * 2, szAcc = (size_t)B * F * 2;
    const size_t needT2 = szW + szBoxes + szH + szAcc;
    const size_t needT3 = szBoxes + szH + szAcc;
    int tier = (ws_size >= needT2) ? 2 : (ws_size >= needT3) ? 3 : 4;
    u16 *WlB = nullptr, *WrB = nullptr, *WsB = nullptr, *SlB = nullptr, *SsB = nullptr;
    const float *WlF = Wl, *WrF = Wr, *WsF = Ws, *SlF = Sl, *SsF = Ss;
    u16* p = ws;
    if (tier == 2) {
      WlB = p; WrB = p + WE; WsB = p + 2 * WE; SlB = p + 3 * WE; SsB = p + 4 * WE;
      p += 5 * WE;
      cvt_bf16<<<WE / 2048, blk, 0, stream>>>(Wl, WlB, (int)WE);
      cvt_bf16<<<WE / 2048, blk, 0, stream>>>(Wr, WrB, (int)WE);
      cvt_bf16<<<WE / 2048, blk, 0, stream>>>(Ws, WsB, (int)WE);
      cvt_bf16<<<WE / 2048, blk, 0, stream>>>(Sl, SlB, (int)WE);
      cvt_bf16<<<WE / 2048, blk, 0, stream>>>(Ss, SsB, (int)WE);
      WlF = WrF = WsF = SlF = SsF = nullptr;
    }
    u16* boxes = p;
    p += B * NB * F;
    u16* hBuf = p; p += B * H;
    u16* accBuf = p;
    box_all_v2<<<B, blk, 0, stream>>>(inp, Wb, bb, boxes);
    const u16* curA = boxes + 63 * 512;
    int curLda = (int)(NB * F);
    for (int bp = 62; bp >= 0; --bp) {
      gemm64<<<gH, blk, 0, stream>>>(curA, curLda, WlB, WlF, 512,
                                     boxes + (long)bp * 512, (int)(NB * F), WrB, WrF, 512,
                                     bl, nullptr, nullptr, nullptr, 1, 0, hBuf, nullptr, 1024);
      gemm64<<<gP, blk, 0, stream>>>(hBuf, 1024, WsB, WsF, 1024,
                                     nullptr, 0, nullptr, nullptr, 0,
                                     bs, nullptr, nullptr, nullptr, 1, 0, accBuf, nullptr, 512);
      curA = accBuf; curLda = 512;
    }
    for (int symp = 15; symp >= 0; --symp) {
      gemm64<<<gH, blk, 0, stream>>>(accBuf, 512, SlB, SlF, 512,
                                     nullptr, 0, nullptr, nullptr, 0,
                                     sbl, sym + symp * 8, Sr, sbr, 1, 0, hBuf, nullptr, 1024);
      int om = (symp == 0) ? 1 : 0;
      gemm64<<<gP, blk, 0, stream>>>(hBuf, 1024, SsB, SsF, 1024,
                                     nullptr, 0, nullptr, nullptr, 0,
                                     sbs, nullptr, nullptr, nullptr, 1, om, accBuf, (float*)d_out, 512);
    }
  }
  (void)in_sizes; (void)n_in; (void)out_size;
}